// Round 16
// baseline (1331.185 us; speedup 1.0000x reference)
//
#include <hip/hip_runtime.h>

// CAGenerator: 64-step neural CA — ONE dispatch per step (R16).
// Step kernel kA (grid 256 x 512 thr, block = one pixel row y of image b):
//   1. stage ch0 halo: aN5 = U_i ch0 rows y-2..y+2, aO5 = Ma_{i-1} rows
//      y-2..y+2; compute live_i for rows y-1..y+1 (maxpool3 > T on both).
//      (first step: live = 1, reference applies no initial mask.)
//   2. stage masked state msT = fp16(U_i * live) for 80ch x 3rows x 34px
//      (zero border), octet layout [cc][p][8ch] -> B-frag = 1 ds_read_b128.
//   3. phase 1: 8 waves compute all 512 H channels for the row
//      (permuted-K kp = tap*80+ci, depth-8 Wc prefetch ring); H -> LDS.
//   4. phase 2: waves 0-2, upd = W3*H full-K in-block;
//      U_{i+1} = U_i*live + upd + b3 (fp32 exact); Ma_i = (U_i*live) ch0.
// finalize: dout = U_64 ch0 * live_64 (from U_64 ch0 + Ma_63).
// No H/Aseed/Smf16 global buffers, no kB, no memcpy.
// Folded: Wc = W2@W1 (512x720), bc = W2@b1+b2. mask=uniform()<1.0 -> no RNG.

#define NPIX 8192
#define T_ALIVE 0.01f

typedef _Float16 f16;
typedef __attribute__((ext_vector_type(8)))  _Float16 h8_t;
typedef __attribute__((ext_vector_type(4)))  _Float16 h4_t;
typedef __attribute__((ext_vector_type(16))) float    fx16;

// ---------------------------------------------------------------------------
// Prep (verified R13-R15)
// ---------------------------------------------------------------------------
__global__ __launch_bounds__(256) void tr512(
    const float* __restrict__ W2, float* __restrict__ W2T)
{
    __shared__ float t[32][33];
    const int bx = blockIdx.x & 15, by = blockIdx.x >> 4;
    const int x = threadIdx.x & 31, y8 = threadIdx.x >> 5;
#pragma unroll
    for (int r = 0; r < 32; r += 8)
        t[r + y8][x] = W2[(size_t)(by * 32 + r + y8) * 512 + bx * 32 + x];
    __syncthreads();
#pragma unroll
    for (int r = 0; r < 32; r += 8)
        W2T[(size_t)(bx * 32 + r + y8) * 512 + by * 32 + x] = t[x][r + y8];
}

__global__ __launch_bounds__(256) void wc32(
    const float* __restrict__ W2T, const float* __restrict__ W1,
    float* __restrict__ Wc)
{
    __shared__ float As[16][32];
    __shared__ float Bs[16][32];
    const int tid = threadIdx.x;
    const int ty = tid >> 3, tx = tid & 7;
    const int m0 = blockIdx.y * 32, n0 = blockIdx.x * 32;
    float acc[4] = {0.f, 0.f, 0.f, 0.f};

    for (int k0 = 0; k0 < 512; k0 += 16) {
#pragma unroll
        for (int t = 0; t < 2; ++t) {
            const int idx = tid + t * 256;
            const int r = idx >> 5, c = idx & 31;
            As[r][c] = W2T[(size_t)(k0 + r) * 512 + m0 + c];
            const int n = n0 + c;
            Bs[r][c] = (n < 720) ? W1[(size_t)(k0 + r) * 720 + n] : 0.f;
        }
        __syncthreads();
#pragma unroll
        for (int kk = 0; kk < 16; ++kk) {
            const float a = As[kk][ty];
#pragma unroll
            for (int j = 0; j < 4; ++j)
                acc[j] = fmaf(a, Bs[kk][tx * 4 + j], acc[j]);
        }
        __syncthreads();
    }
    const int m = m0 + ty;
#pragma unroll
    for (int j = 0; j < 4; ++j) {
        const int n = n0 + tx * 4 + j;
        if (n < 720) Wc[(size_t)m * 720 + n] = acc[j];
    }
}

__global__ __launch_bounds__(256) void bc_k(
    const float* __restrict__ W2, const float* __restrict__ b1,
    const float* __restrict__ b2, float* __restrict__ bc)
{
    const int m = blockIdx.x * 256 + threadIdx.x;
    if (m >= 512) return;
    float a = b2[m];
    for (int h = 0; h < 512; ++h) a += W2[m * 512 + h] * b1[h];
    bc[m] = a;
}

// 32x32x16 A-frags, K permuted (kp = tap*80+ci), 720 = 45*16 exactly.
__global__ __launch_bounds__(256) void swz_wc2(
    const float* __restrict__ Wc, f16* __restrict__ Wcsw2)
{
    const int idx = blockIdx.x * 256 + threadIdx.x;
    if (idx >= 45 * 16 * 64) return;
    const int lane = idx & 63;
    const int t = idx >> 6;
    const int mtg = t & 15, ks = t >> 4;
    const int m = mtg * 32 + (lane & 31);
    const int k0 = ks * 16 + (lane >> 5) * 8;
    h8_t v;
#pragma unroll
    for (int j = 0; j < 8; ++j) {
        const int kp = k0 + j;
        const int tap = kp / 80, ci = kp - tap * 80;
        v[j] = (f16)Wc[(size_t)m * 720 + ci * 9 + tap];
    }
    *(h8_t*)(Wcsw2 + (size_t)idx * 8) = v;
}

// 32x32x16 A-frags for W3 (80x512 padded to 96 rows).
__global__ __launch_bounds__(256) void swz_w32(
    const float* __restrict__ W3, f16* __restrict__ W3sw2)
{
    const int idx = blockIdx.x * 256 + threadIdx.x;
    if (idx >= 32 * 3 * 64) return;
    const int lane = idx & 63;
    const int t = idx >> 6;
    const int mt = t % 3, ks2 = t / 3;
    const int m = mt * 32 + (lane & 31);
    const int k0 = ks2 * 16 + (lane >> 5) * 8;
    h8_t v;
#pragma unroll
    for (int j = 0; j < 8; ++j)
        v[j] = (f16)((m < 80) ? W3[(size_t)m * 512 + k0 + j] : 0.f);
    *(h8_t*)(W3sw2 + (size_t)idx * 8) = v;
}

__global__ __launch_bounds__(256) void seed_k(
    const float* __restrict__ z, float* __restrict__ U0)
{
    const int idx = blockIdx.x * 256 + threadIdx.x;
    if (idx >= 640) return;
    const int b = idx / 80, c = idx - b * 80;
    const int n = b * 1024 + 16 * 32 + 16;
    U0[(size_t)c * NPIX + n] = (c == 0) ? 1.f : z[b * 100 + (c - 1)];
}

// ---------------------------------------------------------------------------
// kA: fused step kernel. grid 256, 512 threads: b = blk>>5, y = blk&31.
// ---------------------------------------------------------------------------
__global__ __launch_bounds__(512) void kA(
    const float* __restrict__ Uprev, const float* __restrict__ MaPrev,
    const f16* __restrict__ Wcsw2, const float* __restrict__ bc,
    const f16* __restrict__ W3sw2, const float* __restrict__ b3,
    float* __restrict__ Ucur, float* __restrict__ MaCur, int first)
{
    __shared__ f16   msT[8160];     // 10 cc x (3 rows x 34 px) x 8 halfs
    __shared__ f16   Hsw[16384];    // 64 co x 32 px x 8 halfs = 32 KB
    __shared__ float bcL[512];
    __shared__ float b3L[80];
    __shared__ float aN5[160];      // U ch0 rows y-2..y+2
    __shared__ float aO5[160];      // Ma_{i-1} rows y-2..y+2
    __shared__ float live3[96];     // live for rows y-1..y+1

    const int tid = threadIdx.x;
    const int lane = tid & 63, w = tid >> 6;     // w = 0..7 (chunk)
    const int li = lane & 31, q2 = lane >> 5;
    const int blk = blockIdx.x;
    const int b = blk >> 5, y = blk & 31;
    const int gb = b * 1024;

    bcL[tid] = bc[tid];
    if (tid < 80) b3L[tid] = b3[tid];
    if (tid < 160) {
        const int r5 = tid >> 5, x = tid & 31, yy = y - 2 + r5;
        const bool inb = (unsigned)yy < 32u;
        aN5[tid] = inb ? Uprev[gb + yy * 32 + x]  : -1e30f;
        aO5[tid] = inb ? MaPrev[gb + yy * 32 + x] : -1e30f;
    }
    __syncthreads();

    // live mask for rows y-1..y+1
    if (tid < 96) {
        const int r3 = tid >> 5, x = tid & 31;
        const int yy = y - 1 + r3;
        float lv = 0.f;
        if ((unsigned)yy < 32u) {
            if (first) lv = 1.f;
            else {
                float mN = -1e30f, mO = -1e30f;
#pragma unroll
                for (int dy = 0; dy <= 2; ++dy)
#pragma unroll
                    for (int dx = -1; dx <= 1; ++dx) {
                        const int xx = x + dx;
                        if ((unsigned)xx < 32u) {
                            mN = fmaxf(mN, aN5[(r3 + dy) * 32 + xx]);
                            mO = fmaxf(mO, aO5[(r3 + dy) * 32 + xx]);
                        }
                    }
                lv = (mN > T_ALIVE && mO > T_ALIVE) ? 1.f : 0.f;
            }
        }
        live3[tid] = lv;
    }
    __syncthreads();

    // Ma_i (own row, masked ch0) for the next step's alphaO
    if (tid < 32)
        MaCur[gb + y * 32 + tid] = Uprev[gb + y * 32 + tid] * live3[32 + tid];

    // border zeros (p = r*34 + {0,33})
    if (tid < 480) {
        const int c = tid / 6, rem = tid - c * 6;
        const int r = rem >> 1, p = r * 34 + ((rem & 1) ? 33 : 0);
        msT[(size_t)(((c >> 3) * 102 + p) * 8) + (c & 7)] = (f16)0.f;
    }
    // bulk masked staging: 80 ch x 3 rows x 32 px
    for (int idx = tid; idx < 7680; idx += 512) {
        const int c = idx / 96, rem = idx - c * 96;
        const int r = rem >> 5, x = rem & 31;
        const int yy = y - 1 + r;
        float v = 0.f;
        if ((unsigned)yy < 32u)
            v = Uprev[(size_t)c * NPIX + gb + yy * 32 + x] * live3[r * 32 + x];
        msT[(size_t)(((c >> 3) * 102 + r * 34 + x + 1) * 8) + (c & 7)] = (f16)v;
    }
    __syncthreads();

    // ---------------- phase 1: H chunk (64 ch x 32 px) per wave -----------
    int pxh[9];
#pragma unroll
    for (int t = 0; t < 9; ++t)
        pxh[t] = ((t / 3) * 34 + li + (t % 3)) * 8;

    fx16 acc[2];
#pragma unroll
    for (int i = 0; i < 2; ++i)
#pragma unroll
        for (int r = 0; r < 16; ++r) acc[i][r] = 0.f;

    h8_t abuf[8][2];                // depth-8 prefetch ring
#pragma unroll
    for (int pk = 0; pk < 8; ++pk)
#pragma unroll
        for (int i = 0; i < 2; ++i)
            abuf[pk][i] = *(const h8_t*)(Wcsw2 +
                (((size_t)pk * 16 + (w * 2 + i)) * 64 + lane) * 8);

#pragma unroll
    for (int ks = 0; ks < 45; ++ks) {
        const int o0 = 2 * ks, o1 = 2 * ks + 1;
        const int a0 = (o0 % 10) * 816 + pxh[o0 / 10];
        const int a1 = (o1 % 10) * 816 + pxh[o1 / 10];
        const h8_t bf = *(const h8_t*)(msT + (q2 ? a1 : a0));
        h8_t av[2];
#pragma unroll
        for (int i = 0; i < 2; ++i) av[i] = abuf[ks & 7][i];
        if (ks + 8 < 45) {
#pragma unroll
            for (int i = 0; i < 2; ++i)
                abuf[ks & 7][i] = *(const h8_t*)(Wcsw2 +
                    (((size_t)(ks + 8) * 16 + (w * 2 + i)) * 64 + lane) * 8);
        }
#pragma unroll
        for (int i = 0; i < 2; ++i)
            acc[i] = __builtin_amdgcn_mfma_f32_32x32x16_f16(
                av[i], bf, acc[i], 0, 0, 0);
    }

    // relu(acc + bc) -> Hsw octet layout
#pragma unroll
    for (int i = 0; i < 2; ++i) {
#pragma unroll
        for (int aa = 0; aa < 4; ++aa) {
            const int chl = i * 32 + 8 * aa + 4 * q2;
            const int co = w * 8 + i * 4 + aa;
            h4_t v4;
#pragma unroll
            for (int rb = 0; rb < 4; ++rb)
                v4[rb] = (f16)fmaxf(acc[i][aa * 4 + rb] + bcL[w * 64 + chl + rb], 0.f);
            *(h4_t*)(Hsw + ((size_t)co * 32 + li) * 8 + 4 * q2) = v4;
        }
    }
    __syncthreads();

    // ---------------- phase 2: upd = W3*H full-K (waves 0..2) -------------
    if (w < 3) {
        const int mt = w;
        h8_t ar[8];
#pragma unroll
        for (int pk = 0; pk < 8; ++pk)
            ar[pk] = *(const h8_t*)(W3sw2 +
                (((size_t)pk * 3 + mt) * 64 + lane) * 8);

        fx16 acc3;
#pragma unroll
        for (int r = 0; r < 16; ++r) acc3[r] = 0.f;
#pragma unroll
        for (int ks2 = 0; ks2 < 32; ++ks2) {
            const h8_t bf = *(const h8_t*)(Hsw +
                ((size_t)(ks2 * 2 + q2) * 32 + li) * 8);
            const h8_t a = ar[ks2 & 7];
            if (ks2 + 8 < 32)
                ar[ks2 & 7] = *(const h8_t*)(W3sw2 +
                    (((size_t)(ks2 + 8) * 3 + mt) * 64 + lane) * 8);
            acc3 = __builtin_amdgcn_mfma_f32_32x32x16_f16(a, bf, acc3, 0, 0, 0);
        }

        // U_{i+1} = U_i*live + upd + b3
        const size_t px = (size_t)(gb + y * 32 + li);
        const float lv = live3[32 + li];
#pragma unroll
        for (int aa = 0; aa < 4; ++aa)
#pragma unroll
            for (int rb = 0; rb < 4; ++rb) {
                const int ch = mt * 32 + rb + 8 * aa + 4 * q2;
                if (ch < 80) {
                    const size_t idx = (size_t)ch * NPIX + px;
                    Ucur[idx] = Uprev[idx] * lv + acc3[aa * 4 + rb] + b3L[ch];
                }
            }
    }
}

// ---------------------------------------------------------------------------
// finalize: dout = U_64 ch0 * live_64 (alphaN = U_64 ch0, alphaO = Ma_63)
// ---------------------------------------------------------------------------
__global__ __launch_bounds__(256) void fin_k(
    const float* __restrict__ U, const float* __restrict__ Ma,
    float* __restrict__ dout)
{
    const int n = blockIdx.x * 256 + threadIdx.x;
    const int b = n >> 10, r = n & 1023;
    const int y = r >> 5, x = r & 31;
    const int gb = b * 1024;
    float mN = -1e30f, mO = -1e30f;
#pragma unroll
    for (int dy = -1; dy <= 1; ++dy) {
        const int yy = y + dy;
        if ((unsigned)yy >= 32u) continue;
#pragma unroll
        for (int dx = -1; dx <= 1; ++dx) {
            const int xx = x + dx;
            if ((unsigned)xx >= 32u) continue;
            mN = fmaxf(mN, U[gb + yy * 32 + xx]);
            mO = fmaxf(mO, Ma[gb + yy * 32 + xx]);
        }
    }
    const float lv = (mN > T_ALIVE && mO > T_ALIVE) ? 1.f : 0.f;
    dout[n] = U[n] * lv;
}

// ---------------------------------------------------------------------------
extern "C" void kernel_launch(void* const* d_in, const int* in_sizes, int n_in,
                              void* d_out, int out_size, void* d_ws, size_t ws_size,
                              hipStream_t stream)
{
    const float* z  = (const float*)d_in[0];
    const float* W1 = (const float*)d_in[1];   // 512 x 720
    const float* b1 = (const float*)d_in[2];
    const float* W2 = (const float*)d_in[3];   // 512 x 512
    const float* b2 = (const float*)d_in[4];
    const float* W3 = (const float*)d_in[5];   // 80 x 512
    const float* b3 = (const float*)d_in[6];

    char* ws = (char*)d_ws;
    float* U0    = (float*)ws;  ws += (size_t)80 * NPIX * 4;
    float* U1    = (float*)ws;  ws += (size_t)80 * NPIX * 4;
    float* Ma0   = (float*)ws;  ws += NPIX * 4;
    float* Ma1   = (float*)ws;  ws += NPIX * 4;
    float* bc    = (float*)ws;  ws += 512 * 4;
    float* Wc    = (float*)ws;  ws += (size_t)512 * 720 * 4;
    float* W2T   = (float*)ws;  ws += (size_t)512 * 512 * 4;
    f16*   Wcsw2 = (f16*)ws;   ws += (size_t)45 * 16 * 64 * 8 * 2;
    f16*   W3sw2 = (f16*)ws;   ws += (size_t)32 * 3 * 64 * 8 * 2;

    hipMemsetAsync(U0, 0, (size_t)80 * NPIX * 4, stream);
    seed_k<<<3, 256, 0, stream>>>(z, U0);
    tr512<<<256, 256, 0, stream>>>(W2, W2T);
    wc32<<<dim3(23, 16), 256, 0, stream>>>(W2T, W1, Wc);
    bc_k<<<2, 256, 0, stream>>>(W2, b1, b2, bc);
    swz_wc2<<<180, 256, 0, stream>>>(Wc, Wcsw2);
    swz_w32<<<24, 256, 0, stream>>>(W3, W3sw2);

    float* Ub[2]  = {U0, U1};
    float* Mab[2] = {Ma0, Ma1};
    for (int i = 0; i < 64; ++i) {
        kA<<<256, 512, 0, stream>>>(Ub[i & 1], Mab[(i + 1) & 1],
                                    Wcsw2, bc, W3sw2, b3,
                                    Ub[(i + 1) & 1], Mab[i & 1],
                                    (i == 0) ? 1 : 0);
    }
    // U_64 lives in Ub[0], Ma_63 in Mab[1]
    fin_k<<<32, 256, 0, stream>>>(Ub[0], Mab[1], (float*)d_out);
}